// Round 11
// baseline (287.033 us; speedup 1.0000x reference)
//
#include <hip/hip_runtime.h>

typedef unsigned short ushort_t;
typedef __attribute__((ext_vector_type(8))) short short8;
typedef __attribute__((ext_vector_type(4))) float f32x4;

__device__ __forceinline__ ushort_t f2b(float f) {           // RTN (accurate)
    union { float f; unsigned int i; } v; v.f = f;
    unsigned int x = v.i;
    return (ushort_t)((x + 0x7fffu + ((x >> 16) & 1u)) >> 16);
}
__device__ __forceinline__ ushort_t f2b_fast(float f) {      // round-half-up
    union { float f; unsigned int i; } v; v.f = f;
    return (ushort_t)((v.i + 0x8000u) >> 16);
}
__device__ __forceinline__ float exp2_hw(float x) {          // v_exp_f32: 2^x
    return __builtin_amdgcn_exp2f(x);
}
// async global->LDS DMA, 16B/lane: lane i reads 16B at its own gptr, writes
// LDS at (wave-uniform) lptr + i*16  [m97 recipe]
__device__ __forceinline__ void dma16(const ushort_t* g, ushort_t* l) {
    __builtin_amdgcn_global_load_lds(
        (const __attribute__((address_space(1))) unsigned int*)g,
        (__attribute__((address_space(3))) unsigned int*)l, 16, 0, 0);
}

// ---------------- fp32 -> bf16 conversion pre-pass ------------------------
__global__ __launch_bounds__(256)
void convert_bf16(const float* __restrict__ hs, const float* __restrict__ wq,
                  const float* __restrict__ wk, const float* __restrict__ wv,
                  const float* __restrict__ wo,
                  ushort_t* __restrict__ hsb, ushort_t* __restrict__ wqb,
                  ushort_t* __restrict__ wkb, ushort_t* __restrict__ wvb,
                  ushort_t* __restrict__ wob)
{
    const int y = blockIdx.y;
    const float* src; ushort_t* dst; int n;
    if (y == 0)      { src = hs; dst = hsb; n = 8192 * 768; }
    else if (y == 1) { src = wq; dst = wqb; n = 768 * 768; }
    else if (y == 2) { src = wk; dst = wkb; n = 768 * 768; }
    else if (y == 3) { src = wv; dst = wvb; n = 768 * 768; }
    else             { src = wo; dst = wob; n = 768 * 768; }
    const int idx = (blockIdx.x * 256 + threadIdx.x) * 8;
    if (idx >= n) return;
    const float4 a = ((const float4*)(src + idx))[0];
    const float4 b = ((const float4*)(src + idx))[1];
    ushort_t tmp[8] = { f2b(a.x), f2b(a.y), f2b(a.z), f2b(a.w),
                        f2b(b.x), f2b(b.y), f2b(b.z), f2b(b.w) };
    *(uint4*)(dst + idx) = *(const uint4*)tmp;
}

// ---------------- MFMA GEMM, m97-style: both operands DMA-staged ----------
// C[m,o] = sum_k A[m,k]*W[o,k] + bias[o].  Block 256 thr / 4 waves;
// tile 128(m) x 128(o) x BK=64; wave tile 64x64 (32 MFMA/iter, frag reuse).
// A and W chunks staged via global_load_lds dwordx4 (8 DMA/wave/iter, no
// VGPR round-trip); LDS granule layout [kg][row] (+1 granule pad per kg
// block) -> DMA writes lane-contiguous, frag ds_read_b128 bank-staggered.
// Two barriers per iter (m97 structure).
// 1-D grid, id = (slot << 3) | xcd: blocks sharing an A m-tile on one XCD.
// MODE 0 (QKV): 1152 blocks; slot -> (mtile group, 6 o-tiles x 3 sets).
//   z=0 -> Q [bh][l][64] * (0.125*log2e); z=1 -> K [bh][l][64];
//   z=2 -> V transposed [bh][64][l]
// MODE 1 (out-proj): 384 blocks; 6 o-tiles; C fp32 [m][768].
#define AKG 129   // granules (16B) per kg block: 128 rows + 1 pad

template<int MODE>
__global__ __launch_bounds__(256, 4)
void gemm_mfma(const ushort_t* __restrict__ A,
               const ushort_t* __restrict__ W0, const ushort_t* __restrict__ W1,
               const ushort_t* __restrict__ W2,
               const float* __restrict__ b0, const float* __restrict__ b1,
               const float* __restrict__ b2,
               void* __restrict__ C0, void* __restrict__ C1, void* __restrict__ C2)
{
    __shared__ __attribute__((aligned(16))) ushort_t Ab[8 * AKG * 8];
    __shared__ __attribute__((aligned(16))) ushort_t Wb[8 * AKG * 8];

    const int id   = blockIdx.x;
    const int xcd  = id & 7;
    const int slot = id >> 3;
    int mtile, otile, z;
    if (MODE == 0) {
        mtile = (slot / 18) * 8 + xcd;
        const int rem = slot % 18;
        otile = rem % 6;
        z     = rem / 6;
    } else {
        mtile = (slot / 6) * 8 + xcd;
        otile = slot % 6;
        z     = 0;
    }
    const ushort_t* W = (z == 0) ? W0 : (z == 1) ? W1 : W2;
    const float* bias  = (z == 0) ? b0 : (z == 1) ? b1 : b2;
    void* C            = (z == 0) ? C0 : (z == 1) ? C1 : C2;

    const int t    = threadIdx.x;
    const int lane = t & 63;
    const int w    = t >> 6;
    const int col  = lane & 15;
    const int kg   = lane >> 4;
    const int m0   = mtile * 128;
    const int o0   = otile * 128;
    const int mh   = (w & 1) * 64;
    const int oh   = (w >> 1) * 64;

    f32x4 acc[4][4];
#pragma unroll
    for (int mt = 0; mt < 4; ++mt)
#pragma unroll
        for (int nt = 0; nt < 4; ++nt) acc[mt][nt] = (f32x4){0.f, 0.f, 0.f, 0.f};

    // DMA source base pointers for this wave (kg blocks 2w, 2w+1; halves 0,1)
    const ushort_t* pa = A + (size_t)(m0 + lane) * 768;
    const ushort_t* pw = W + (size_t)(o0 + lane) * 768;

    for (int it = 0; it < 12; ++it) {
        const int k0 = it * 64;
        if (it) __syncthreads();   // all waves done reading previous chunk
#pragma unroll
        for (int kgl = 0; kgl < 2; ++kgl) {
            const int kgi = 2 * w + kgl;
#pragma unroll
            for (int h = 0; h < 2; ++h) {
                dma16(pa + (size_t)h * 64 * 768 + k0 + kgi * 8,
                      &Ab[(kgi * AKG + h * 64) * 8]);
                dma16(pw + (size_t)h * 64 * 768 + k0 + kgi * 8,
                      &Wb[(kgi * AKG + h * 64) * 8]);
            }
        }
        __syncthreads();           // vmcnt(0) drain -> chunk visible

        short8 wf[4][2];
#pragma unroll
        for (int nt = 0; nt < 4; ++nt) {
            wf[nt][0] = *(const short8*)&Wb[((kg)     * AKG + oh + nt * 16 + col) * 8];
            wf[nt][1] = *(const short8*)&Wb[((kg + 4) * AKG + oh + nt * 16 + col) * 8];
        }
#pragma unroll
        for (int mt = 0; mt < 4; ++mt) {
            const short8 a0 = *(const short8*)&Ab[((kg)     * AKG + mh + mt * 16 + col) * 8];
            const short8 a1 = *(const short8*)&Ab[((kg + 4) * AKG + mh + mt * 16 + col) * 8];
#pragma unroll
            for (int nt = 0; nt < 4; ++nt) {
                acc[mt][nt] = __builtin_amdgcn_mfma_f32_16x16x32_bf16(
                    a0, wf[nt][0], acc[mt][nt], 0, 0, 0);
                acc[mt][nt] = __builtin_amdgcn_mfma_f32_16x16x32_bf16(
                    a1, wf[nt][1], acc[mt][nt], 0, 0, 0);
            }
        }
    }

    float bias_v[4];
#pragma unroll
    for (int nt = 0; nt < 4; ++nt) bias_v[nt] = bias[o0 + oh + nt * 16 + col];
    // Q prescale: 1/8 (attn scale) * log2(e), so attn softmax can use exp2
    const float scale = (MODE == 0 && z == 0) ? 0.18033688011112042f : 1.0f;

#pragma unroll
    for (int mt = 0; mt < 4; ++mt)
#pragma unroll
        for (int nt = 0; nt < 4; ++nt) {
            const int mb = m0 + mh + mt * 16 + kg * 4;
            const int o  = o0 + oh + nt * 16 + col;
            if (MODE == 0 && z == 2) {
                ushort_t tmp[4];
#pragma unroll
                for (int r = 0; r < 4; ++r) tmp[r] = f2b(acc[mt][nt][r] + bias_v[nt]);
                const size_t dst = ((size_t)((mb >> 11) * 12 + (o >> 6)) << 17)
                                 + ((size_t)(o & 63) << 11) + (mb & 2047);
                *(uint2*)((ushort_t*)C + dst) = *(const uint2*)tmp;
            } else {
#pragma unroll
                for (int r = 0; r < 4; ++r) {
                    const int m = mb + r;
                    const float v = (acc[mt][nt][r] + bias_v[nt]) * scale;
                    if (MODE == 0) {
                        const size_t dst = ((size_t)((m >> 11) * 12 + (o >> 6)) << 17)
                                         + ((size_t)(m & 2047) << 6) + (o & 63);
                        ((ushort_t*)C)[dst] = f2b(v);
                    } else {
                        ((float*)C)[(size_t)m * 768 + o] = v;
                    }
                }
            }
        }
}

// ---------------- MFMA flash attention (round-8/9 verified) ---------------
// Q: [48][2048][64] bf16 pre-scaled by 0.125*log2e. K: [48][2048][64].
// Vt: [48][64][2048]. AO: [4][2048][768] bf16.
// 1-D grid of 768; 16 pair-blocks of one bh land on one XCD (K/V L2-resident).
// Block = 2 paired 64-row q-tiles (31-p, p) -> uniform 33 chunks per block.
#define KV_STRIDE 72
#define PS_STRIDE 76

__global__ __launch_bounds__(256, 3)
void attn_mfma(const ushort_t* __restrict__ Q, const ushort_t* __restrict__ K,
               const ushort_t* __restrict__ Vt, ushort_t* __restrict__ AO)
{
    __shared__ ushort_t Ks[64 * KV_STRIDE];        // K chunk [key][d]
    __shared__ ushort_t Vs[64 * KV_STRIDE];        // V chunk [d][key]
    __shared__ ushort_t Ps[4][16 * PS_STRIDE];     // per-wave P tile [q][key]

    const int t    = threadIdx.x;
    const int lane = t & 63;
    const int w    = t >> 6;
    const int id   = blockIdx.x;
    const int bh   = ((id >> 3) >> 4) * 8 + (id & 7);   // 16 blocks/bh on one XCD
    const int p    = (id >> 3) & 15;                    // pair id 0..15
    const size_t base = (size_t)bh << 17;

    const int col = lane & 15;
    const int kg  = lane >> 4;
    const int srow = t >> 2;                       // staging row 0..63
    const int scol = (t & 3) << 4;                 // staging col 0/16/32/48
    const int b = bh / 12, h = bh % 12;

#pragma unroll
    for (int phase = 0; phase < 2; ++phase) {
        const int tile = phase ? p : (31 - p);     // heavy tile first
        const int q0   = tile << 6;
        const int nch  = tile + 1;

        // Q A-frag for this wave's 16 rows
        const ushort_t* pq = Q + base + (size_t)(q0 + 16 * w + col) * 64 + kg * 8;
        const short8 aq0 = *(const short8*)pq;
        const short8 aq1 = *(const short8*)(pq + 32);

        float l_lane[4] = {0.f, 0.f, 0.f, 0.f};
        f32x4 o_acc[4];
#pragma unroll
        for (int vt = 0; vt < 4; ++vt) o_acc[vt] = (f32x4){0.f, 0.f, 0.f, 0.f};

        // preload chunk 0
        uint4 ka, kb, va, vb;
        {
            const ushort_t* pk = K  + base + (size_t)srow * 64 + scol;
            const ushort_t* pv = Vt + base + ((size_t)srow << 11) + scol;
            ka = *(const uint4*)pk; kb = *(const uint4*)(pk + 8);
            va = *(const uint4*)pv; vb = *(const uint4*)(pv + 8);
        }

        for (int c = 0; c < nch; ++c) {
            __syncthreads();   // previous chunk's LDS reads complete
            *(uint4*)&Ks[srow * KV_STRIDE + scol]     = ka;
            *(uint4*)&Ks[srow * KV_STRIDE + scol + 8] = kb;
            *(uint4*)&Vs[srow * KV_STRIDE + scol]     = va;
            *(uint4*)&Vs[srow * KV_STRIDE + scol + 8] = vb;
            __syncthreads();   // chunk staged

            if (c + 1 < nch) {   // prefetch next chunk (overlaps compute)
                const int k1 = (c + 1) << 6;
                const ushort_t* pk = K  + base + (size_t)(k1 + srow) * 64 + scol;
                const ushort_t* pv = Vt + base + ((size_t)srow << 11) + k1 + scol;
                ka = *(const uint4*)pk; kb = *(const uint4*)(pk + 8);
                va = *(const uint4*)pv; vb = *(const uint4*)(pv + 8);
            }

            // S = (Q * 0.125*log2e) K^T
            f32x4 s[4];
#pragma unroll
            for (int kt = 0; kt < 4; ++kt) {
                const ushort_t* pkf = &Ks[(kt * 16 + col) * KV_STRIDE + kg * 8];
                const short8 b0 = *(const short8*)pkf;
                const short8 b1 = *(const short8*)(pkf + 32);
                f32x4 acc = (f32x4){0.f, 0.f, 0.f, 0.f};
                acc = __builtin_amdgcn_mfma_f32_16x16x32_bf16(aq0, b0, acc, 0, 0, 0);
                acc = __builtin_amdgcn_mfma_f32_16x16x32_bf16(aq1, b1, acc, 0, 0, 0);
                s[kt] = acc;
            }

            // P = exp2(S); causal mask only on the diagonal (last) chunk
            const int qrow = q0 + 16 * w + 4 * kg;
            if (c == nch - 1) {
                const int k0 = c << 6;
#pragma unroll
                for (int kt = 0; kt < 4; ++kt)
#pragma unroll
                    for (int r = 0; r < 4; ++r) {
                        const int key = k0 + kt * 16 + col;
                        s[kt][r] = (key > qrow + r) ? 0.f : exp2_hw(s[kt][r]);
                    }
            } else {
#pragma unroll
                for (int kt = 0; kt < 4; ++kt)
#pragma unroll
                    for (int r = 0; r < 4; ++r) s[kt][r] = exp2_hw(s[kt][r]);
            }
#pragma unroll
            for (int r = 0; r < 4; ++r)
                l_lane[r] += (s[0][r] + s[1][r]) + (s[2][r] + s[3][r]);

            // P: C-layout -> LDS -> A-layout (wave-internal)
            ushort_t* ps = Ps[w];
#pragma unroll
            for (int kt = 0; kt < 4; ++kt)
#pragma unroll
                for (int r = 0; r < 4; ++r)
                    ps[(4 * kg + r) * PS_STRIDE + kt * 16 + col] = f2b_fast(s[kt][r]);
            short8 pa0, pa1;
            {
                const ushort_t* pp = ps + (size_t)col * PS_STRIDE + kg * 8;
                pa0 = *(const short8*)pp;
                pa1 = *(const short8*)(pp + 32);
            }

            // O += P V
#pragma unroll
            for (int vt = 0; vt < 4; ++vt) {
                const ushort_t* pvf = &Vs[(vt * 16 + col) * KV_STRIDE + kg * 8];
                const short8 v0 = *(const short8*)pvf;
                const short8 v1 = *(const short8*)(pvf + 32);
                f32x4 o = o_acc[vt];
                o = __builtin_amdgcn_mfma_f32_16x16x32_bf16(pa0, v0, o, 0, 0, 0);
                o = __builtin_amdgcn_mfma_f32_16x16x32_bf16(pa1, v1, o, 0, 0, 0);
                o_acc[vt] = o;
            }
        }

        // l reduction (once per phase) + normalize + store
        float linv[4];
#pragma unroll
        for (int r = 0; r < 4; ++r) {
            float ls = l_lane[r];
            ls += __shfl_xor(ls, 1);
            ls += __shfl_xor(ls, 2);
            ls += __shfl_xor(ls, 4);
            ls += __shfl_xor(ls, 8);
            linv[r] = 1.f / ls;
        }
#pragma unroll
        for (int vt = 0; vt < 4; ++vt)
#pragma unroll
            for (int r = 0; r < 4; ++r) {
                const int q = q0 + 16 * w + 4 * kg + r;
                AO[((size_t)(b * 2048 + q)) * 768 + h * 64 + vt * 16 + col] =
                    f2b_fast(o_acc[vt][r] * linv[r]);
            }
    }
}

extern "C" void kernel_launch(void* const* d_in, const int* in_sizes, int n_in,
                              void* d_out, int out_size, void* d_ws, size_t ws_size,
                              hipStream_t stream) {
    const float* hs = (const float*)d_in[0];
    const float* wq = (const float*)d_in[1];
    const float* bq = (const float*)d_in[2];
    const float* wk = (const float*)d_in[3];
    const float* bk = (const float*)d_in[4];
    const float* wv = (const float*)d_in[5];
    const float* bv = (const float*)d_in[6];
    const float* wo = (const float*)d_in[7];
    const float* bo = (const float*)d_in[8];
    float* out = (float*)d_out;

    const size_t NB = (size_t)8192 * 768;
    const size_t WN = (size_t)768 * 768;
    ushort_t* hsb = (ushort_t*)d_ws;        // aliased: becomes AO after QKV GEMMs
    ushort_t* Qb  = hsb + NB;
    ushort_t* Kb  = Qb + NB;
    ushort_t* Vtb = Kb + NB;                // V transposed [48][64][2048]
    ushort_t* wqb = Vtb + NB;
    ushort_t* wkb = wqb + WN;
    ushort_t* wvb = wkb + WN;
    ushort_t* wob = wvb + WN;
    ushort_t* AO  = hsb;                    // hs_bf16 dead once attn runs

    dim3 blk(256);
    convert_bf16<<<dim3(3072, 5), blk, 0, stream>>>(hs, wq, wk, wv, wo,
                                                    hsb, wqb, wkb, wvb, wob);
    gemm_mfma<0><<<dim3(1152), blk, 0, stream>>>(hsb, wqb, wkb, wvb,
                                                 bq, bk, bv, Qb, Kb, Vtb);
    attn_mfma<<<dim3(768), blk, 0, stream>>>(Qb, Kb, Vtb, AO);
    gemm_mfma<1><<<dim3(384), blk, 0, stream>>>(AO, wob, wob, wob,
                                                bo, bo, bo, out, out, out);
}

// Round 12
// 273.337 us; speedup vs baseline: 1.0501x; 1.0501x over previous
//
#include <hip/hip_runtime.h>

typedef unsigned short ushort_t;
typedef __attribute__((ext_vector_type(8))) short short8;
typedef __attribute__((ext_vector_type(4))) float f32x4;

__device__ __forceinline__ ushort_t f2b(float f) {           // RTN (accurate)
    union { float f; unsigned int i; } v; v.f = f;
    unsigned int x = v.i;
    return (ushort_t)((x + 0x7fffu + ((x >> 16) & 1u)) >> 16);
}
__device__ __forceinline__ ushort_t f2b_fast(float f) {      // round-half-up
    union { float f; unsigned int i; } v; v.f = f;
    return (ushort_t)((v.i + 0x8000u) >> 16);
}
__device__ __forceinline__ float exp2_hw(float x) {          // v_exp_f32: 2^x
    return __builtin_amdgcn_exp2f(x);
}
// async global->LDS DMA, 16B/lane: lane i reads 16B at its own gptr, writes
// LDS at (wave-uniform) lptr + i*16  [m97 recipe]
__device__ __forceinline__ void dma16(const ushort_t* g, ushort_t* l) {
    __builtin_amdgcn_global_load_lds(
        (const __attribute__((address_space(1))) unsigned int*)g,
        (__attribute__((address_space(3))) unsigned int*)l, 16, 0, 0);
}

// ---------------- fp32 -> bf16 conversion pre-pass ------------------------
__global__ __launch_bounds__(256)
void convert_bf16(const float* __restrict__ hs, const float* __restrict__ wq,
                  const float* __restrict__ wk, const float* __restrict__ wv,
                  const float* __restrict__ wo,
                  ushort_t* __restrict__ hsb, ushort_t* __restrict__ wqb,
                  ushort_t* __restrict__ wkb, ushort_t* __restrict__ wvb,
                  ushort_t* __restrict__ wob)
{
    const int y = blockIdx.y;
    const float* src; ushort_t* dst; int n;
    if (y == 0)      { src = hs; dst = hsb; n = 8192 * 768; }
    else if (y == 1) { src = wq; dst = wqb; n = 768 * 768; }
    else if (y == 2) { src = wk; dst = wkb; n = 768 * 768; }
    else if (y == 3) { src = wv; dst = wvb; n = 768 * 768; }
    else             { src = wo; dst = wob; n = 768 * 768; }
    const int idx = (blockIdx.x * 256 + threadIdx.x) * 8;
    if (idx >= n) return;
    const float4 a = ((const float4*)(src + idx))[0];
    const float4 b = ((const float4*)(src + idx))[1];
    ushort_t tmp[8] = { f2b(a.x), f2b(a.y), f2b(a.z), f2b(a.w),
                        f2b(b.x), f2b(b.y), f2b(b.z), f2b(b.w) };
    *(uint4*)(dst + idx) = *(const uint4*)tmp;
}

// ---------------- MFMA GEMM, DMA-staged + DOUBLE-BUFFERED K-loop ----------
// C[m,o] = sum_k A[m,k]*W[o,k] + bias[o].  Block 256 thr / 4 waves;
// tile 128(m) x 128(o) x BK=64; wave tile 64x64 (32 MFMA/iter).
// Both operands staged via global_load_lds dwordx4 into 2 LDS buffers:
// per iter: barrier (drains DMAs issued LAST iter -> latency already hidden
// under a full compute phase) -> ds_read frags -> issue next-chunk DMAs ->
// 32 MFMA. 66 KB LDS -> 2 blocks/CU.
// 1-D grid, id = (slot << 3) | xcd: blocks sharing an A m-tile on one XCD.
// MODE 0 (QKV): 1152 blocks. z=0 -> Q [bh][l][64] * (0.125*log2e);
//   z=1 -> K [bh][l][64]; z=2 -> V transposed [bh][64][l]
// MODE 1 (out-proj): 384 blocks; C fp32 [m][768].
#define AKG 129   // granules (16B) per kg block: 128 rows + 1 pad

template<int MODE>
__global__ __launch_bounds__(256, 2)
void gemm_mfma(const ushort_t* __restrict__ A,
               const ushort_t* __restrict__ W0, const ushort_t* __restrict__ W1,
               const ushort_t* __restrict__ W2,
               const float* __restrict__ b0, const float* __restrict__ b1,
               const float* __restrict__ b2,
               void* __restrict__ C0, void* __restrict__ C1, void* __restrict__ C2)
{
    __shared__ __attribute__((aligned(16))) ushort_t Ab[2][8 * AKG * 8];
    __shared__ __attribute__((aligned(16))) ushort_t Wb[2][8 * AKG * 8];

    const int id   = blockIdx.x;
    const int xcd  = id & 7;
    const int slot = id >> 3;
    int mtile, otile, z;
    if (MODE == 0) {
        mtile = (slot / 18) * 8 + xcd;
        const int rem = slot % 18;
        otile = rem % 6;
        z     = rem / 6;
    } else {
        mtile = (slot / 6) * 8 + xcd;
        otile = slot % 6;
        z     = 0;
    }
    const ushort_t* W = (z == 0) ? W0 : (z == 1) ? W1 : W2;
    const float* bias  = (z == 0) ? b0 : (z == 1) ? b1 : b2;
    void* C            = (z == 0) ? C0 : (z == 1) ? C1 : C2;

    const int t    = threadIdx.x;
    const int lane = t & 63;
    const int w    = t >> 6;
    const int col  = lane & 15;
    const int kg   = lane >> 4;
    const int m0   = mtile * 128;
    const int o0   = otile * 128;
    const int mh   = (w & 1) * 64;
    const int oh   = (w >> 1) * 64;

    f32x4 acc[4][4];
#pragma unroll
    for (int mt = 0; mt < 4; ++mt)
#pragma unroll
        for (int nt = 0; nt < 4; ++nt) acc[mt][nt] = (f32x4){0.f, 0.f, 0.f, 0.f};

    // DMA source base pointers for this wave (kg blocks 2w, 2w+1; halves 0,1)
    const ushort_t* pa = A + (size_t)(m0 + lane) * 768;
    const ushort_t* pw = W + (size_t)(o0 + lane) * 768;

    {   // prologue: DMA chunk 0 into buffer 0
#pragma unroll
        for (int kgl = 0; kgl < 2; ++kgl) {
            const int kgi = 2 * w + kgl;
#pragma unroll
            for (int h = 0; h < 2; ++h) {
                dma16(pa + (size_t)h * 64 * 768 + kgi * 8,
                      &Ab[0][(kgi * AKG + h * 64) * 8]);
                dma16(pw + (size_t)h * 64 * 768 + kgi * 8,
                      &Wb[0][(kgi * AKG + h * 64) * 8]);
            }
        }
    }

    for (int it = 0; it < 12; ++it) {
        const int cur = it & 1, nxt = cur ^ 1;
        __syncthreads();   // drains DMA(chunk it) issued one iteration ago

        // frag loads from current buffer (lgkm-gated, independent of DMAs)
        short8 wf[4][2], af[4][2];
#pragma unroll
        for (int nt = 0; nt < 4; ++nt) {
            wf[nt][0] = *(const short8*)&Wb[cur][((kg)     * AKG + oh + nt * 16 + col) * 8];
            wf[nt][1] = *(const short8*)&Wb[cur][((kg + 4) * AKG + oh + nt * 16 + col) * 8];
        }
#pragma unroll
        for (int mt = 0; mt < 4; ++mt) {
            af[mt][0] = *(const short8*)&Ab[cur][((kg)     * AKG + mh + mt * 16 + col) * 8];
            af[mt][1] = *(const short8*)&Ab[cur][((kg + 4) * AKG + mh + mt * 16 + col) * 8];
        }

        if (it < 11) {   // issue next chunk's DMAs; they fly during the MFMAs
            const int kn = (it + 1) * 64;
#pragma unroll
            for (int kgl = 0; kgl < 2; ++kgl) {
                const int kgi = 2 * w + kgl;
#pragma unroll
                for (int h = 0; h < 2; ++h) {
                    dma16(pa + (size_t)h * 64 * 768 + kn + kgi * 8,
                          &Ab[nxt][(kgi * AKG + h * 64) * 8]);
                    dma16(pw + (size_t)h * 64 * 768 + kn + kgi * 8,
                          &Wb[nxt][(kgi * AKG + h * 64) * 8]);
                }
            }
        }

#pragma unroll
        for (int mt = 0; mt < 4; ++mt)
#pragma unroll
            for (int nt = 0; nt < 4; ++nt) {
                acc[mt][nt] = __builtin_amdgcn_mfma_f32_16x16x32_bf16(
                    af[mt][0], wf[nt][0], acc[mt][nt], 0, 0, 0);
                acc[mt][nt] = __builtin_amdgcn_mfma_f32_16x16x32_bf16(
                    af[mt][1], wf[nt][1], acc[mt][nt], 0, 0, 0);
            }
    }

    float bias_v[4];
#pragma unroll
    for (int nt = 0; nt < 4; ++nt) bias_v[nt] = bias[o0 + oh + nt * 16 + col];
    // Q prescale: 1/8 (attn scale) * log2(e), so attn softmax can use exp2
    const float scale = (MODE == 0 && z == 0) ? 0.18033688011112042f : 1.0f;

#pragma unroll
    for (int mt = 0; mt < 4; ++mt)
#pragma unroll
        for (int nt = 0; nt < 4; ++nt) {
            const int mb = m0 + mh + mt * 16 + kg * 4;
            const int o  = o0 + oh + nt * 16 + col;
            if (MODE == 0 && z == 2) {
                ushort_t tmp[4];
#pragma unroll
                for (int r = 0; r < 4; ++r) tmp[r] = f2b(acc[mt][nt][r] + bias_v[nt]);
                const size_t dst = ((size_t)((mb >> 11) * 12 + (o >> 6)) << 17)
                                 + ((size_t)(o & 63) << 11) + (mb & 2047);
                *(uint2*)((ushort_t*)C + dst) = *(const uint2*)tmp;
            } else {
#pragma unroll
                for (int r = 0; r < 4; ++r) {
                    const int m = mb + r;
                    const float v = (acc[mt][nt][r] + bias_v[nt]) * scale;
                    if (MODE == 0) {
                        const size_t dst = ((size_t)((m >> 11) * 12 + (o >> 6)) << 17)
                                         + ((size_t)(m & 2047) << 6) + (o & 63);
                        ((ushort_t*)C)[dst] = f2b(v);
                    } else {
                        ((float*)C)[(size_t)m * 768 + o] = v;
                    }
                }
            }
        }
}

// ---------------- MFMA flash attention (round-8/9 verified) ---------------
// Q: [48][2048][64] bf16 pre-scaled by 0.125*log2e. K: [48][2048][64].
// Vt: [48][64][2048]. AO: [4][2048][768] bf16.
// 1-D grid of 768; 16 pair-blocks of one bh land on one XCD (K/V L2-resident).
// Block = 2 paired 64-row q-tiles (31-p, p) -> uniform 33 chunks per block.
#define KV_STRIDE 72
#define PS_STRIDE 76

__global__ __launch_bounds__(256, 3)
void attn_mfma(const ushort_t* __restrict__ Q, const ushort_t* __restrict__ K,
               const ushort_t* __restrict__ Vt, ushort_t* __restrict__ AO)
{
    __shared__ ushort_t Ks[64 * KV_STRIDE];        // K chunk [key][d]
    __shared__ ushort_t Vs[64 * KV_STRIDE];        // V chunk [d][key]
    __shared__ ushort_t Ps[4][16 * PS_STRIDE];     // per-wave P tile [q][key]

    const int t    = threadIdx.x;
    const int lane = t & 63;
    const int w    = t >> 6;
    const int id   = blockIdx.x;
    const int bh   = ((id >> 3) >> 4) * 8 + (id & 7);   // 16 blocks/bh on one XCD
    const int p    = (id >> 3) & 15;                    // pair id 0..15
    const size_t base = (size_t)bh << 17;

    const int col = lane & 15;
    const int kg  = lane >> 4;
    const int srow = t >> 2;                       // staging row 0..63
    const int scol = (t & 3) << 4;                 // staging col 0/16/32/48
    const int b = bh / 12, h = bh % 12;

#pragma unroll
    for (int phase = 0; phase < 2; ++phase) {
        const int tile = phase ? p : (31 - p);     // heavy tile first
        const int q0   = tile << 6;
        const int nch  = tile + 1;

        // Q A-frag for this wave's 16 rows
        const ushort_t* pq = Q + base + (size_t)(q0 + 16 * w + col) * 64 + kg * 8;
        const short8 aq0 = *(const short8*)pq;
        const short8 aq1 = *(const short8*)(pq + 32);

        float l_lane[4] = {0.f, 0.f, 0.f, 0.f};
        f32x4 o_acc[4];
#pragma unroll
        for (int vt = 0; vt < 4; ++vt) o_acc[vt] = (f32x4){0.f, 0.f, 0.f, 0.f};

        // preload chunk 0
        uint4 ka, kb, va, vb;
        {
            const ushort_t* pk = K  + base + (size_t)srow * 64 + scol;
            const ushort_t* pv = Vt + base + ((size_t)srow << 11) + scol;
            ka = *(const uint4*)pk; kb = *(const uint4*)(pk + 8);
            va = *(const uint4*)pv; vb = *(const uint4*)(pv + 8);
        }

        for (int c = 0; c < nch; ++c) {
            __syncthreads();   // previous chunk's LDS reads complete
            *(uint4*)&Ks[srow * KV_STRIDE + scol]     = ka;
            *(uint4*)&Ks[srow * KV_STRIDE + scol + 8] = kb;
            *(uint4*)&Vs[srow * KV_STRIDE + scol]     = va;
            *(uint4*)&Vs[srow * KV_STRIDE + scol + 8] = vb;
            __syncthreads();   // chunk staged

            if (c + 1 < nch) {   // prefetch next chunk (overlaps compute)
                const int k1 = (c + 1) << 6;
                const ushort_t* pk = K  + base + (size_t)(k1 + srow) * 64 + scol;
                const ushort_t* pv = Vt + base + ((size_t)srow << 11) + k1 + scol;
                ka = *(const uint4*)pk; kb = *(const uint4*)(pk + 8);
                va = *(const uint4*)pv; vb = *(const uint4*)(pv + 8);
            }

            // S = (Q * 0.125*log2e) K^T
            f32x4 s[4];
#pragma unroll
            for (int kt = 0; kt < 4; ++kt) {
                const ushort_t* pkf = &Ks[(kt * 16 + col) * KV_STRIDE + kg * 8];
                const short8 b0 = *(const short8*)pkf;
                const short8 b1 = *(const short8*)(pkf + 32);
                f32x4 acc = (f32x4){0.f, 0.f, 0.f, 0.f};
                acc = __builtin_amdgcn_mfma_f32_16x16x32_bf16(aq0, b0, acc, 0, 0, 0);
                acc = __builtin_amdgcn_mfma_f32_16x16x32_bf16(aq1, b1, acc, 0, 0, 0);
                s[kt] = acc;
            }

            // P = exp2(S); causal mask only on the diagonal (last) chunk
            const int qrow = q0 + 16 * w + 4 * kg;
            if (c == nch - 1) {
                const int k0 = c << 6;
#pragma unroll
                for (int kt = 0; kt < 4; ++kt)
#pragma unroll
                    for (int r = 0; r < 4; ++r) {
                        const int key = k0 + kt * 16 + col;
                        s[kt][r] = (key > qrow + r) ? 0.f : exp2_hw(s[kt][r]);
                    }
            } else {
#pragma unroll
                for (int kt = 0; kt < 4; ++kt)
#pragma unroll
                    for (int r = 0; r < 4; ++r) s[kt][r] = exp2_hw(s[kt][r]);
            }
#pragma unroll
            for (int r = 0; r < 4; ++r)
                l_lane[r] += (s[0][r] + s[1][r]) + (s[2][r] + s[3][r]);

            // P: C-layout -> LDS -> A-layout (wave-internal)
            ushort_t* ps = Ps[w];
#pragma unroll
            for (int kt = 0; kt < 4; ++kt)
#pragma unroll
                for (int r = 0; r < 4; ++r)
                    ps[(4 * kg + r) * PS_STRIDE + kt * 16 + col] = f2b_fast(s[kt][r]);
            short8 pa0, pa1;
            {
                const ushort_t* pp = ps + (size_t)col * PS_STRIDE + kg * 8;
                pa0 = *(const short8*)pp;
                pa1 = *(const short8*)(pp + 32);
            }

            // O += P V
#pragma unroll
            for (int vt = 0; vt < 4; ++vt) {
                const ushort_t* pvf = &Vs[(vt * 16 + col) * KV_STRIDE + kg * 8];
                const short8 v0 = *(const short8*)pvf;
                const short8 v1 = *(const short8*)(pvf + 32);
                f32x4 o = o_acc[vt];
                o = __builtin_amdgcn_mfma_f32_16x16x32_bf16(pa0, v0, o, 0, 0, 0);
                o = __builtin_amdgcn_mfma_f32_16x16x32_bf16(pa1, v1, o, 0, 0, 0);
                o_acc[vt] = o;
            }
        }

        // l reduction (once per phase) + normalize + store
        float linv[4];
#pragma unroll
        for (int r = 0; r < 4; ++r) {
            float ls = l_lane[r];
            ls += __shfl_xor(ls, 1);
            ls += __shfl_xor(ls, 2);
            ls += __shfl_xor(ls, 4);
            ls += __shfl_xor(ls, 8);
            linv[r] = 1.f / ls;
        }
#pragma unroll
        for (int vt = 0; vt < 4; ++vt)
#pragma unroll
            for (int r = 0; r < 4; ++r) {
                const int q = q0 + 16 * w + 4 * kg + r;
                AO[((size_t)(b * 2048 + q)) * 768 + h * 64 + vt * 16 + col] =
                    f2b_fast(o_acc[vt][r] * linv[r]);
            }
    }
}

extern "C" void kernel_launch(void* const* d_in, const int* in_sizes, int n_in,
                              void* d_out, int out_size, void* d_ws, size_t ws_size,
                              hipStream_t stream) {
    const float* hs = (const float*)d_in[0];
    const float* wq = (const float*)d_in[1];
    const float* bq = (const float*)d_in[2];
    const float* wk = (const float*)d_in[3];
    const float* bk = (const float*)d_in[4];
    const float* wv = (const float*)d_in[5];
    const float* bv = (const float*)d_in[6];
    const float* wo = (const float*)d_in[7];
    const float* bo = (const float*)d_in[8];
    float* out = (float*)d_out;

    const size_t NB = (size_t)8192 * 768;
    const size_t WN = (size_t)768 * 768;
    ushort_t* hsb = (ushort_t*)d_ws;        // aliased: becomes AO after QKV GEMMs
    ushort_t* Qb  = hsb + NB;
    ushort_t* Kb  = Qb + NB;
    ushort_t* Vtb = Kb + NB;                // V transposed [48][64][2048]
    ushort_t* wqb = Vtb + NB;
    ushort_t* wkb = wqb + WN;
    ushort_t* wvb = wkb + WN;
    ushort_t* wob = wvb + WN;
    ushort_t* AO  = hsb;                    // hs_bf16 dead once attn runs

    dim3 blk(256);
    convert_bf16<<<dim3(3072, 5), blk, 0, stream>>>(hs, wq, wk, wv, wo,
                                                    hsb, wqb, wkb, wvb, wob);
    gemm_mfma<0><<<dim3(1152), blk, 0, stream>>>(hsb, wqb, wkb, wvb,
                                                 bq, bk, bv, Qb, Kb, Vtb);
    attn_mfma<<<dim3(768), blk, 0, stream>>>(Qb, Kb, Vtb, AO);
    gemm_mfma<1><<<dim3(384), blk, 0, stream>>>(AO, wob, wob, wob,
                                                bo, bo, bo, out, out, out);
}